// Round 3
// baseline (912.438 us; speedup 1.0000x reference)
//
#include <hip/hip_runtime.h>
#include <hip/hip_bf16.h>

// Problem constants (from reference)
#define NPTS   160000    // B*P = 4*40000
#define DIM    128
#define HID    512
#define KK2    49        // 7x7
#define DEPTH  2

typedef __attribute__((ext_vector_type(8))) short bf16x8;
typedef __attribute__((ext_vector_type(4))) float f32x4;

static __device__ __forceinline__ ushort f2bf(float f) {
    unsigned u = __float_as_uint(f);
    return (ushort)((u + 0x7fffu + ((u >> 16) & 1u)) >> 16);
}
static __device__ __forceinline__ float bf2f(ushort h) {
    return __uint_as_float(((unsigned)h) << 16);
}
static __device__ __forceinline__ float lo16(unsigned u) { return __uint_as_float(u << 16); }
static __device__ __forceinline__ float hi16(unsigned u) { return __uint_as_float(u & 0xffff0000u); }

// Fast GELU: exact form 0.5v(1+erf(v/sqrt2)) with A&S 7.1.26 erf
// (max |err| 1.5e-7 -- indistinguishable from libm erff at bf16 output).
// ~16 VALU ops, branch-free, vs ~35 for __ocml erff.
static __device__ __forceinline__ float gelu_f(float v) {
    float x  = v * 0.70710678118654752f;
    float ax = fabsf(x);
    float t  = __builtin_amdgcn_rcpf(1.0f + 0.3275911f * ax);
    float p  = t * (0.254829592f + t * (-0.284496736f +
               t * (1.421413741f + t * (-1.453152027f + t * 1.061405429f))));
    float e  = __expf(-ax * ax);
    float er = copysignf(1.0f - p * e, x);
    return 0.5f * v * (1.0f + er);
}

// ---------------------------------------------------------------------------
// fp32 -> bf16 cast (4 elems/thread), exact-size grid
// ---------------------------------------------------------------------------
__global__ __launch_bounds__(256) void cast_bf16_kernel(
    const float* __restrict__ x, ushort* __restrict__ o)
{
    int i = blockIdx.x * 256 + threadIdx.x;
    float4 v = ((const float4*)x)[i];
    ushort4 r;
    r.x = f2bf(v.x); r.y = f2bf(v.y); r.z = f2bf(v.z); r.w = f2bf(v.w);
    ((ushort4*)o)[i] = r;
}

// ---------------------------------------------------------------------------
// transpose w1 (128x512 fp32) -> w1t (512x128 bf16, n-major); also zeros ssq
// ---------------------------------------------------------------------------
__global__ void w1t_kernel(const float* __restrict__ w1, ushort* __restrict__ w1t,
                           float* __restrict__ ssq) {
    int n = blockIdx.x;            // 0..511
    int k = threadIdx.x;           // 0..127
    w1t[n * 128 + k] = f2bf(w1[k * 512 + n]);
    if (n < 4) ssq[n * 128 + k] = 0.f;
}

// ---------------------------------------------------------------------------
// Compact valid neighbor taps into round-of-4 entries:
//   entry = idx*256 + tap   (idx*256 = byte offset of X row; tap in low 8b)
// padded to a multiple of 4 with entry 49 (idx 0, tap 49 = zero weight row).
// wl stride = 52 ints/token; nrounds[n] = ceil(cnt/4).  One wave per token.
// ---------------------------------------------------------------------------
__global__ __launch_bounds__(256) void compact2_kernel(
    const int* __restrict__ nbr, int* __restrict__ wl, int* __restrict__ nrounds)
{
    const int tid = threadIdx.x, lane = tid & 63, wv = tid >> 6;
    const int n = blockIdx.x * 4 + wv;
    int idx = (lane < KK2) ? nbr[(size_t)n * KK2 + lane] : NPTS;
    bool valid = idx < NPTS;
    unsigned long long mask = __ballot(valid);
    int cnt = __popcll(mask);
    int pos = __popcll(mask & ((1ull << lane) - 1ull));
    int* row = wl + (size_t)n * 52;
    if (valid) row[pos] = (idx << 8) | lane;
    int padded = (cnt + 3) & ~3;
    if (lane < padded - cnt) row[cnt + lane] = 49;
    if (lane == 0) nrounds[n] = padded >> 2;
}

// ---------------------------------------------------------------------------
// Depthwise sparse conv + LayerNorm, v3 (unchanged this round).
// ---------------------------------------------------------------------------
__global__ __launch_bounds__(1024) void dwln3_kernel(
    const ushort* __restrict__ X,      // N x 128 bf16
    const int*    __restrict__ wl,     // N x 52 entries
    const int*    __restrict__ nrounds,// N
    const float*  __restrict__ wdw,    // 49 x 128 fp32
    const float*  __restrict__ bdw,    // 128
    const float*  __restrict__ lng,    // 128
    const float*  __restrict__ lnb,    // 128
    ushort*       __restrict__ y1)     // N x 128 bf16
{
    __shared__ __align__(16) float wsm[16 * 50 * 8];   // [cg][tap][8]
    const int tid = threadIdx.x;
    #pragma unroll
    for (int i0 = 0; i0 < 2048; i0 += 1024) {
        int i = i0 + tid;
        if (i < 1568) {
            int tap = i >> 5, rem = i & 31, cg = rem >> 1, q = rem & 1;
            ((float4*)wsm)[(cg * 50 + tap) * 2 + q] = ((const float4*)wdw)[i];
        }
    }
    if (tid < 32) {
        float4 z = {0.f, 0.f, 0.f, 0.f};
        int cg = tid >> 1, q = tid & 1;
        ((float4*)wsm)[(cg * 50 + 49) * 2 + q] = z;
    }
    __syncthreads();

    const int lane = tid & 63, wv = tid >> 6;
    const int n = blockIdx.x * 16 + wv;
    const int slot = lane >> 4, cg = lane & 15;
    const int R = nrounds[n];
    const int* row = wl + (size_t)n * 52;
    const float* wcg = wsm + cg * 400;
    const char* Xb = (const char*)X + cg * 16;

    float a[8] = {0.f, 0.f, 0.f, 0.f, 0.f, 0.f, 0.f, 0.f};

    int e0 = row[slot];
    int e1 = (R > 1) ? row[4 + slot] : 49;
    uint4 x0 = *(const uint4*)(Xb + (e0 & ~255));
    for (int r = 0; r < R; ++r) {
        int e2 = (r + 2 < R) ? row[(r + 2) * 4 + slot] : 49;
        uint4 x1 = {0u, 0u, 0u, 0u};
        if (r + 1 < R) x1 = *(const uint4*)(Xb + (e1 & ~255));
        const float* wp = wcg + (e0 & 255) * 8;
        float4 wa = *(const float4*)wp;
        float4 wb = *(const float4*)(wp + 4);
        a[0] += lo16(x0.x) * wa.x;  a[1] += hi16(x0.x) * wa.y;
        a[2] += lo16(x0.y) * wa.z;  a[3] += hi16(x0.y) * wa.w;
        a[4] += lo16(x0.z) * wb.x;  a[5] += hi16(x0.z) * wb.y;
        a[6] += lo16(x0.w) * wb.z;  a[7] += hi16(x0.w) * wb.w;
        e0 = e1; e1 = e2; x0 = x1;
    }

    // combine the 4 tap-slots (lanes with equal cg)
    #pragma unroll
    for (int j = 0; j < 8; ++j) {
        a[j] += __shfl_xor(a[j], 16);
        a[j] += __shfl_xor(a[j], 32);
    }

    const float4 bda = ((const float4*)bdw)[cg * 2];
    const float4 bdb = ((const float4*)bdw)[cg * 2 + 1];
    a[0] += bda.x; a[1] += bda.y; a[2] += bda.z; a[3] += bda.w;
    a[4] += bdb.x; a[5] += bdb.y; a[6] += bdb.z; a[7] += bdb.w;

    float s1 = 0.f, s2 = 0.f;
    #pragma unroll
    for (int j = 0; j < 8; ++j) { s1 += a[j]; s2 += a[j] * a[j]; }
    #pragma unroll
    for (int m = 1; m < 16; m <<= 1) {
        s1 += __shfl_xor(s1, m);
        s2 += __shfl_xor(s2, m);
    }
    const float mu  = s1 * (1.f / 128.f);
    const float var = s2 * (1.f / 128.f) - mu * mu;
    const float rs  = rsqrtf(var + 1e-6f);

    if (slot == 0) {
        const float4 ga = ((const float4*)lng)[cg * 2];
        const float4 gb = ((const float4*)lng)[cg * 2 + 1];
        const float4 ba = ((const float4*)lnb)[cg * 2];
        const float4 bb = ((const float4*)lnb)[cg * 2 + 1];
        uint4 r;
        r.x = (unsigned)f2bf((a[0] - mu) * rs * ga.x + ba.x)
            | ((unsigned)f2bf((a[1] - mu) * rs * ga.y + ba.y) << 16);
        r.y = (unsigned)f2bf((a[2] - mu) * rs * ga.z + ba.z)
            | ((unsigned)f2bf((a[3] - mu) * rs * ga.w + ba.w) << 16);
        r.z = (unsigned)f2bf((a[4] - mu) * rs * gb.x + bb.x)
            | ((unsigned)f2bf((a[5] - mu) * rs * gb.y + bb.y) << 16);
        r.w = (unsigned)f2bf((a[6] - mu) * rs * gb.z + bb.z)
            | ((unsigned)f2bf((a[7] - mu) * rs * gb.w + bb.w) << 16);
        ((uint4*)(y1 + (size_t)n * DIM))[cg] = r;
    }
}

// ---------------------------------------------------------------------------
// GEMM1 v4: B-only LDS staging (32KB, XOR-swizzled) with T14 split-stage
// prefetch (next tile's B issued to regs BEFORE current tile's MFMA+epilogue,
// ds_write after the barrier), A direct global->reg loaded once (K=128),
// fast A&S-erf GELU.  grid = NPTS/128.
// ---------------------------------------------------------------------------
__global__ __launch_bounds__(256) void gemm1_kernel(
    const ushort* __restrict__ y1,    // N x 128 bf16
    const ushort* __restrict__ w1t,   // 512 x 128 bf16 (n-major)
    const float*  __restrict__ b1,    // 512 fp32
    ushort*       __restrict__ y2,    // N x 512 bf16
    float*        __restrict__ ssq)   // 512 fp32
{
    __shared__ __align__(16) ushort sB[128 * 128];   // 32 KB
    __shared__ float sred[HID];
    const int tid = threadIdx.x;
    const int lane = tid & 63, wv = tid >> 6;
    const int lr = lane & 15, q = lane >> 4;
    const int m0 = blockIdx.x << 7;
    const int mw = m0 + (wv << 5);

    #pragma unroll
    for (int i = tid; i < HID; i += 256) sred[i] = 0.f;

    // A fragments: lane holds row (mw + rt*16 + lr), k = ks*32 + q*8 .. +8
    bf16x8 af[2][4];
    {
        const ushort* a0 = y1 + (size_t)(mw + lr) * DIM + (q << 3);
        #pragma unroll
        for (int rt = 0; rt < 2; ++rt)
            #pragma unroll
            for (int ks = 0; ks < 4; ++ks)
                af[rt][ks] = *(const bf16x8*)(a0 + rt * 16 * DIM + ks * 32);
    }

    // prologue: stage B tile 0
    #pragma unroll
    for (int i0 = 0; i0 < 2048; i0 += 256) {
        int i = i0 + tid;
        int row = i >> 4, c = i & 15;
        *(uint4*)(sB + row * 128 + ((c ^ (row & 15)) << 3)) =
            *(const uint4*)(w1t + (size_t)row * DIM + (c << 3));
    }
    __syncthreads();

    #pragma unroll 1
    for (int nt = 0; nt < 4; ++nt) {
        // prefetch next B tile to regs (latency hides under MFMA + epilogue)
        uint4 pf[8];
        if (nt < 3) {
            #pragma unroll
            for (int j = 0; j < 8; ++j) {
                int i = (j << 8) + tid;
                int row = i >> 4, c = i & 15;
                pf[j] = *(const uint4*)(w1t + (size_t)(((nt + 1) << 7) + row) * DIM + (c << 3));
            }
        }
        // bias loads in flight during MFMA
        float b1v[8];
        #pragma unroll
        for (int ct = 0; ct < 8; ++ct) b1v[ct] = b1[(nt << 7) + (ct << 4) + lr];

        f32x4 acc[2][8];
        #pragma unroll
        for (int ct = 0; ct < 8; ++ct) { f32x4 z = {0.f,0.f,0.f,0.f}; acc[0][ct] = z; acc[1][ct] = z; }

        #pragma unroll
        for (int ct = 0; ct < 8; ++ct)
            #pragma unroll
            for (int ks = 0; ks < 4; ++ks) {
                const int cidx = ((((ks << 2) + q) ^ lr) << 3);
                bf16x8 bfv = *(const bf16x8*)(sB + ((ct << 4) + lr) * 128 + cidx);
                acc[0][ct] = __builtin_amdgcn_mfma_f32_16x16x32_bf16(af[0][ks], bfv, acc[0][ct], 0, 0, 0);
                acc[1][ct] = __builtin_amdgcn_mfma_f32_16x16x32_bf16(af[1][ks], bfv, acc[1][ct], 0, 0, 0);
            }

        // epilogue: bias + fast GELU + store + ssq partials
        #pragma unroll
        for (int ct = 0; ct < 8; ++ct) {
            const int col = (nt << 7) + (ct << 4) + lr;
            float ss = 0.f;
            #pragma unroll
            for (int rt = 0; rt < 2; ++rt) {
                #pragma unroll
                for (int r = 0; r < 4; ++r) {
                    float g = gelu_f(acc[rt][ct][r] + b1v[ct]);
                    y2[(size_t)(mw + rt * 16 + (q << 2) + r) * HID + col] = f2bf(g);
                    ss += g * g;
                }
            }
            ss += __shfl_xor(ss, 16);
            ss += __shfl_xor(ss, 32);
            if (q == 0) atomicAdd(&sred[col], ss);
        }
        __syncthreads();               // waves done reading sB; sred safe at nt==3
        if (nt < 3) {
            #pragma unroll
            for (int j = 0; j < 8; ++j) {
                int i = (j << 8) + tid;
                int row = i >> 4, c = i & 15;
                *(uint4*)(sB + row * 128 + ((c ^ (row & 15)) << 3)) = pf[j];
            }
            __syncthreads();
        }
    }

    #pragma unroll
    for (int i = tid; i < HID; i += 256) atomicAdd(&ssq[i], sred[i]);
}

// ---------------------------------------------------------------------------
// GRN scale: s[c] = grn_g[c] * nx[c] + 1
// ---------------------------------------------------------------------------
__global__ void grn_prep_kernel(const float* __restrict__ ssq,
                                const float* __restrict__ grn_g,
                                float* __restrict__ s)
{
    __shared__ float red[9];
    const int tid = threadIdx.x;
    const float gx = sqrtf(ssq[tid]);
    float v = gx;
    #pragma unroll
    for (int m = 1; m < 64; m <<= 1) v += __shfl_xor(v, m);
    if ((tid & 63) == 0) red[tid >> 6] = v;
    __syncthreads();
    if (tid == 0) {
        float t = 0.f;
        for (int i = 0; i < 8; ++i) t += red[i];
        red[8] = t;
    }
    __syncthreads();
    const float mean = red[8] * (1.f / 512.f);
    s[tid] = grn_g[tid] * (gx / (mean + 1e-6f)) + 1.0f;
}

// ---------------------------------------------------------------------------
// Fold GRN scale into w2 (transposed, n-major, bf16) + constant bias vector
// ---------------------------------------------------------------------------
__global__ __launch_bounds__(256) void prep_w2_kernel(
    const float* __restrict__ s,      // 512
    const float* __restrict__ w2,     // 512 x 128 fp32 (k-major)
    const float* __restrict__ grn_b,  // 512 fp32
    const float* __restrict__ b2,     // 128 fp32
    ushort*      __restrict__ w2st,   // 128 x 512 bf16 (n-major, scaled)
    float*       __restrict__ bvec)   // 128 fp32
{
    __shared__ float r4[4];
    const int j = blockIdx.x;
    const int tid = threadIdx.x;
    float part = 0.f;
    for (int k = tid; k < HID; k += 256) {
        float wv = w2[k * 128 + j];
        w2st[j * HID + k] = f2bf(s[k] * wv);
        part += grn_b[k] * wv;
    }
    #pragma unroll
    for (int m = 1; m < 64; m <<= 1) part += __shfl_xor(part, m);
    if ((tid & 63) == 0) r4[tid >> 6] = part;
    __syncthreads();
    if (tid == 0)
        bvec[j] = r4[0] + r4[1] + r4[2] + r4[3] + b2[j];
}

// ---------------------------------------------------------------------------
// GEMM2 v4: B-only LDS staging with T14 split-stage prefetch; A fragments
// double-buffered in regs one K-chunk ahead. Fully unrolled K loop (4 chunks).
// out = y2_grn @ w2 + bvec + residual (GRN scale folded into w2st).
// grid = NPTS/128.
// ---------------------------------------------------------------------------
__global__ __launch_bounds__(256) void gemm2_kernel(
    const ushort* __restrict__ y2,      // N x 512 bf16
    const ushort* __restrict__ w2st,    // 128 x 512 bf16 (n-major)
    const float*  __restrict__ bvec,    // 128
    const ushort* __restrict__ resid,   // N x 128 bf16
    float*        __restrict__ outf,    // N x 128 fp32 (or null)
    ushort*       __restrict__ xbfout)  // N x 128 bf16 (or null)
{
    __shared__ __align__(16) ushort sB[128 * 128];   // 32 KB: 128 n x 128 k chunk
    const int tid = threadIdx.x;
    const int lane = tid & 63, wv = tid >> 6;
    const int lr = lane & 15, q = lane >> 4;
    const int m0 = blockIdx.x << 7;
    const int mw = m0 + (wv << 5);

    f32x4 acc[2][8];
    #pragma unroll
    for (int ct = 0; ct < 8; ++ct) { f32x4 z = {0.f,0.f,0.f,0.f}; acc[0][ct] = z; acc[1][ct] = z; }

    const ushort* abase = y2 + (size_t)(mw + lr) * HID + (q << 3);

    // A fragments for chunk 0 (issue first: HBM latency overlaps B staging)
    bf16x8 af[2][2][4];
    #pragma unroll
    for (int rt = 0; rt < 2; ++rt)
        #pragma unroll
        for (int ks = 0; ks < 4; ++ks)
            af[0][rt][ks] = *(const bf16x8*)(abase + rt * 16 * HID + ks * 32);

    // prologue: stage B chunk 0
    #pragma unroll
    for (int i0 = 0; i0 < 2048; i0 += 256) {
        int i = i0 + tid;
        int row = i >> 4, c = i & 15;
        *(uint4*)(sB + row * 128 + ((c ^ (row & 15)) << 3)) =
            *(const uint4*)(w2st + (size_t)row * HID + (c << 3));
    }
    __syncthreads();

    #pragma unroll
    for (int kk = 0; kk < 4; ++kk) {
        const int cur = kk & 1, nxt = cur ^ 1;
        uint4 pf[8];
        if (kk < 3) {
            // prefetch next B chunk to regs
            #pragma unroll
            for (int j = 0; j < 8; ++j) {
                int i = (j << 8) + tid;
                int row = i >> 4, c = i & 15;
                pf[j] = *(const uint4*)(w2st + (size_t)row * HID + ((kk + 1) << 7) + (c << 3));
            }
            // prefetch next A fragments
            #pragma unroll
            for (int rt = 0; rt < 2; ++rt)
                #pragma unroll
                for (int ks = 0; ks < 4; ++ks)
                    af[nxt][rt][ks] = *(const bf16x8*)(abase + rt * 16 * HID + ((kk + 1) << 7) + ks * 32);
        }

        #pragma unroll
        for (int ct = 0; ct < 8; ++ct)
            #pragma unroll
            for (int ks = 0; ks < 4; ++ks) {
                const int cidx = ((((ks << 2) + q) ^ lr) << 3);
                bf16x8 bfv = *(const bf16x8*)(sB + ((ct << 4) + lr) * 128 + cidx);
                acc[0][ct] = __builtin_amdgcn_mfma_f32_16x16x32_bf16(af[cur][0][ks], bfv, acc[0][ct], 0, 0, 0);
                acc[1][ct] = __builtin_amdgcn_mfma_f32_16x16x32_bf16(af[cur][1][ks], bfv, acc[1][ct], 0, 0, 0);
            }
        __syncthreads();
        if (kk < 3) {
            #pragma unroll
            for (int j = 0; j < 8; ++j) {
                int i = (j << 8) + tid;
                int row = i >> 4, c = i & 15;
                *(uint4*)(sB + row * 128 + ((c ^ (row & 15)) << 3)) = pf[j];
            }
            __syncthreads();
        }
    }

    float bv[8];
    #pragma unroll
    for (int ct = 0; ct < 8; ++ct) bv[ct] = bvec[(ct << 4) + lr];

    #pragma unroll
    for (int rt = 0; rt < 2; ++rt)
        #pragma unroll
        for (int r = 0; r < 4; ++r) {
            const int m = mw + (rt << 4) + (q << 2) + r;
            const size_t base = (size_t)m * DIM;
            #pragma unroll
            for (int ct = 0; ct < 8; ++ct) {
                const int j = (ct << 4) + lr;
                float v = acc[rt][ct][r] + bv[ct] + bf2f(resid[base + j]);
                if (outf)   outf[base + j] = v;
                if (xbfout) xbfout[base + j] = f2bf(v);
            }
        }
}

// ---------------------------------------------------------------------------
extern "C" void kernel_launch(void* const* d_in, const int* in_sizes, int n_in,
                              void* d_out, int out_size, void* d_ws, size_t ws_size,
                              hipStream_t stream)
{
    const float* feats = (const float*)d_in[0];
    const float* w_dw  = (const float*)d_in[1];
    const float* b_dw  = (const float*)d_in[2];
    const float* ln_g  = (const float*)d_in[3];
    const float* ln_b  = (const float*)d_in[4];
    const float* w1    = (const float*)d_in[5];
    const float* b1    = (const float*)d_in[6];
    const float* grn_g = (const float*)d_in[7];
    const float* grn_b = (const float*)d_in[8];
    const float* w2    = (const float*)d_in[9];
    const float* b2    = (const float*)d_in[10];
    const int*   nbr   = (const int*)d_in[11];

    char* ws = (char*)d_ws;
    size_t o = 0;
    ushort* y2    = (ushort*)(ws + o); o += (size_t)NPTS * HID * 2;        // 160 MB
    ushort* y1    = (ushort*)(ws + o); o += (size_t)NPTS * DIM * 2;        //  40 MB
    ushort* xbf   = (ushort*)(ws + o); o += (size_t)NPTS * DIM * 2;        //  40 MB
    int*    wl    = (int*)   (ws + o); o += ((size_t)NPTS * 52 + 64) * 4;  //  33 MB
    int*    nrnd  = (int*)   (ws + o); o += (size_t)NPTS * 4;
    ushort* w1t   = (ushort*)(ws + o); o += (size_t)HID * DIM * 2;
    ushort* w2st  = (ushort*)(ws + o); o += (size_t)HID * DIM * 2;
    float*  sbuf  = (float*) (ws + o); o += 2048;
    float*  ssq   = (float*) (ws + o); o += 2048;
    float*  bvec  = (float*) (ws + o); o += 512;

    cast_bf16_kernel<<<NPTS * DIM / 4 / 256, 256, 0, stream>>>(feats, xbf);
    compact2_kernel<<<NPTS / 4, 256, 0, stream>>>(nbr, wl, nrnd);

    for (int l = 0; l < DEPTH; ++l) {
        const float* wdw_l = w_dw  + (size_t)l * KK2 * DIM;
        const float* bdw_l = b_dw  + (size_t)l * DIM;
        const float* lng_l = ln_g  + (size_t)l * DIM;
        const float* lnb_l = ln_b  + (size_t)l * DIM;
        const float* w1_l  = w1    + (size_t)l * DIM * HID;
        const float* b1_l  = b1    + (size_t)l * HID;
        const float* gg_l  = grn_g + (size_t)l * HID;
        const float* gb_l  = grn_b + (size_t)l * HID;
        const float* w2_l  = w2    + (size_t)l * HID * DIM;
        const float* b2_l  = b2    + (size_t)l * DIM;

        w1t_kernel<<<512, 128, 0, stream>>>(w1_l, w1t, ssq);
        dwln3_kernel<<<NPTS / 16, 1024, 0, stream>>>(
            xbf, wl, nrnd, wdw_l, bdw_l, lng_l, lnb_l, y1);
        gemm1_kernel<<<NPTS / 128, 256, 0, stream>>>(y1, w1t, b1_l, y2, ssq);
        grn_prep_kernel<<<1, 512, 0, stream>>>(ssq, gg_l, sbuf);
        prep_w2_kernel<<<128, 256, 0, stream>>>(sbuf, w2_l, gb_l, b2_l, w2st, bvec);
        if (l == 0) {
            gemm2_kernel<<<NPTS / 128, 256, 0, stream>>>(
                y2, w2st, bvec, xbf, nullptr, xbf);
        } else {
            gemm2_kernel<<<NPTS / 128, 256, 0, stream>>>(
                y2, w2st, bvec, xbf, (float*)d_out, nullptr);
        }
    }
}

// Round 4
// 776.462 us; speedup vs baseline: 1.1751x; 1.1751x over previous
//
#include <hip/hip_runtime.h>
#include <hip/hip_bf16.h>

// Problem constants (from reference)
#define NPTS   160000    // B*P = 4*40000
#define DIM    128
#define HID    512
#define KK2    49        // 7x7
#define DEPTH  2

typedef __attribute__((ext_vector_type(8))) short bf16x8;
typedef __attribute__((ext_vector_type(4))) float f32x4;

static __device__ __forceinline__ ushort f2bf(float f) {
    unsigned u = __float_as_uint(f);
    return (ushort)((u + 0x7fffu + ((u >> 16) & 1u)) >> 16);
}
static __device__ __forceinline__ float bf2f(ushort h) {
    return __uint_as_float(((unsigned)h) << 16);
}
static __device__ __forceinline__ float lo16(unsigned u) { return __uint_as_float(u << 16); }
static __device__ __forceinline__ float hi16(unsigned u) { return __uint_as_float(u & 0xffff0000u); }

// Fast GELU: exact form 0.5v(1+erf(v/sqrt2)) with A&S 7.1.26 erf
// (max |err| 1.5e-7 -- indistinguishable from libm erff at bf16 output).
// ~16 VALU ops, branch-free, vs ~35 for __ocml erff.
static __device__ __forceinline__ float gelu_f(float v) {
    float x  = v * 0.70710678118654752f;
    float ax = fabsf(x);
    float t  = __builtin_amdgcn_rcpf(1.0f + 0.3275911f * ax);
    float p  = t * (0.254829592f + t * (-0.284496736f +
               t * (1.421413741f + t * (-1.453152027f + t * 1.061405429f))));
    float e  = __expf(-ax * ax);
    float er = copysignf(1.0f - p * e, x);
    return 0.5f * v * (1.0f + er);
}

// ---------------------------------------------------------------------------
// fp32 -> bf16 cast (4 elems/thread), exact-size grid
// ---------------------------------------------------------------------------
__global__ __launch_bounds__(256) void cast_bf16_kernel(
    const float* __restrict__ x, ushort* __restrict__ o)
{
    int i = blockIdx.x * 256 + threadIdx.x;
    float4 v = ((const float4*)x)[i];
    ushort4 r;
    r.x = f2bf(v.x); r.y = f2bf(v.y); r.z = f2bf(v.z); r.w = f2bf(v.w);
    ((ushort4*)o)[i] = r;
}

// ---------------------------------------------------------------------------
// transpose w1 (128x512 fp32) -> w1t (512x128 bf16, n-major); also zeros ssq
// ---------------------------------------------------------------------------
__global__ void w1t_kernel(const float* __restrict__ w1, ushort* __restrict__ w1t,
                           float* __restrict__ ssq) {
    int n = blockIdx.x;            // 0..511
    int k = threadIdx.x;           // 0..127
    w1t[n * 128 + k] = f2bf(w1[k * 512 + n]);
    if (n < 4) ssq[n * 128 + k] = 0.f;
}

// ---------------------------------------------------------------------------
// Compact valid neighbor taps into round-of-4 entries:
//   entry = idx*256 + tap   (idx*256 = byte offset of X row; tap in low 8b)
// padded to a multiple of 4 with entry 49 (idx 0, tap 49 = zero weight row).
// wl stride = 52 ints/token; nrounds[n] = ceil(cnt/4).  One wave per token.
// ---------------------------------------------------------------------------
__global__ __launch_bounds__(256) void compact2_kernel(
    const int* __restrict__ nbr, int* __restrict__ wl, int* __restrict__ nrounds)
{
    const int tid = threadIdx.x, lane = tid & 63, wv = tid >> 6;
    const int n = blockIdx.x * 4 + wv;
    int idx = (lane < KK2) ? nbr[(size_t)n * KK2 + lane] : NPTS;
    bool valid = idx < NPTS;
    unsigned long long mask = __ballot(valid);
    int cnt = __popcll(mask);
    int pos = __popcll(mask & ((1ull << lane) - 1ull));
    int* row = wl + (size_t)n * 52;
    if (valid) row[pos] = (idx << 8) | lane;
    int padded = (cnt + 3) & ~3;
    if (lane < padded - cnt) row[cnt + lane] = 49;
    if (lane == 0) nrounds[n] = padded >> 2;
}

// ---------------------------------------------------------------------------
// Depthwise sparse conv + LayerNorm, v3 (unchanged this round).
// ---------------------------------------------------------------------------
__global__ __launch_bounds__(1024) void dwln3_kernel(
    const ushort* __restrict__ X,      // N x 128 bf16
    const int*    __restrict__ wl,     // N x 52 entries
    const int*    __restrict__ nrounds,// N
    const float*  __restrict__ wdw,    // 49 x 128 fp32
    const float*  __restrict__ bdw,    // 128
    const float*  __restrict__ lng,    // 128
    const float*  __restrict__ lnb,    // 128
    ushort*       __restrict__ y1)     // N x 128 bf16
{
    __shared__ __align__(16) float wsm[16 * 50 * 8];   // [cg][tap][8]
    const int tid = threadIdx.x;
    #pragma unroll
    for (int i0 = 0; i0 < 2048; i0 += 1024) {
        int i = i0 + tid;
        if (i < 1568) {
            int tap = i >> 5, rem = i & 31, cg = rem >> 1, q = rem & 1;
            ((float4*)wsm)[(cg * 50 + tap) * 2 + q] = ((const float4*)wdw)[i];
        }
    }
    if (tid < 32) {
        float4 z = {0.f, 0.f, 0.f, 0.f};
        int cg = tid >> 1, q = tid & 1;
        ((float4*)wsm)[(cg * 50 + 49) * 2 + q] = z;
    }
    __syncthreads();

    const int lane = tid & 63, wv = tid >> 6;
    const int n = blockIdx.x * 16 + wv;
    const int slot = lane >> 4, cg = lane & 15;
    const int R = nrounds[n];
    const int* row = wl + (size_t)n * 52;
    const float* wcg = wsm + cg * 400;
    const char* Xb = (const char*)X + cg * 16;

    float a[8] = {0.f, 0.f, 0.f, 0.f, 0.f, 0.f, 0.f, 0.f};

    int e0 = row[slot];
    int e1 = (R > 1) ? row[4 + slot] : 49;
    uint4 x0 = *(const uint4*)(Xb + (e0 & ~255));
    for (int r = 0; r < R; ++r) {
        int e2 = (r + 2 < R) ? row[(r + 2) * 4 + slot] : 49;
        uint4 x1 = {0u, 0u, 0u, 0u};
        if (r + 1 < R) x1 = *(const uint4*)(Xb + (e1 & ~255));
        const float* wp = wcg + (e0 & 255) * 8;
        float4 wa = *(const float4*)wp;
        float4 wb = *(const float4*)(wp + 4);
        a[0] += lo16(x0.x) * wa.x;  a[1] += hi16(x0.x) * wa.y;
        a[2] += lo16(x0.y) * wa.z;  a[3] += hi16(x0.y) * wa.w;
        a[4] += lo16(x0.z) * wb.x;  a[5] += hi16(x0.z) * wb.y;
        a[6] += lo16(x0.w) * wb.z;  a[7] += hi16(x0.w) * wb.w;
        e0 = e1; e1 = e2; x0 = x1;
    }

    // combine the 4 tap-slots (lanes with equal cg)
    #pragma unroll
    for (int j = 0; j < 8; ++j) {
        a[j] += __shfl_xor(a[j], 16);
        a[j] += __shfl_xor(a[j], 32);
    }

    const float4 bda = ((const float4*)bdw)[cg * 2];
    const float4 bdb = ((const float4*)bdw)[cg * 2 + 1];
    a[0] += bda.x; a[1] += bda.y; a[2] += bda.z; a[3] += bda.w;
    a[4] += bdb.x; a[5] += bdb.y; a[6] += bdb.z; a[7] += bdb.w;

    float s1 = 0.f, s2 = 0.f;
    #pragma unroll
    for (int j = 0; j < 8; ++j) { s1 += a[j]; s2 += a[j] * a[j]; }
    #pragma unroll
    for (int m = 1; m < 16; m <<= 1) {
        s1 += __shfl_xor(s1, m);
        s2 += __shfl_xor(s2, m);
    }
    const float mu  = s1 * (1.f / 128.f);
    const float var = s2 * (1.f / 128.f) - mu * mu;
    const float rs  = rsqrtf(var + 1e-6f);

    if (slot == 0) {
        const float4 ga = ((const float4*)lng)[cg * 2];
        const float4 gb = ((const float4*)lng)[cg * 2 + 1];
        const float4 ba = ((const float4*)lnb)[cg * 2];
        const float4 bb = ((const float4*)lnb)[cg * 2 + 1];
        uint4 r;
        r.x = (unsigned)f2bf((a[0] - mu) * rs * ga.x + ba.x)
            | ((unsigned)f2bf((a[1] - mu) * rs * ga.y + ba.y) << 16);
        r.y = (unsigned)f2bf((a[2] - mu) * rs * ga.z + ba.z)
            | ((unsigned)f2bf((a[3] - mu) * rs * ga.w + ba.w) << 16);
        r.z = (unsigned)f2bf((a[4] - mu) * rs * gb.x + bb.x)
            | ((unsigned)f2bf((a[5] - mu) * rs * gb.y + bb.y) << 16);
        r.w = (unsigned)f2bf((a[6] - mu) * rs * gb.z + bb.z)
            | ((unsigned)f2bf((a[7] - mu) * rs * gb.w + bb.w) << 16);
        ((uint4*)(y1 + (size_t)n * DIM))[cg] = r;
    }
}

// ---------------------------------------------------------------------------
// GEMM1 v5 = v3 structure (measured best) + fast-erf GELU.
// B-only LDS staging (32KB, XOR-swizzled), A direct global->reg loaded once
// (K=128).  Block = 128 rows x all 512 cols, swept as 4 n-tiles of 128 cols.
// NO register prefetch: round-3 showed it costs occupancy (VGPR 80->120,
// gemm regressed) -- compiler + block TLP hide the stage latency better.
// grid = NPTS/128.
// ---------------------------------------------------------------------------
__global__ __launch_bounds__(256) void gemm1_kernel(
    const ushort* __restrict__ y1,    // N x 128 bf16
    const ushort* __restrict__ w1t,   // 512 x 128 bf16 (n-major)
    const float*  __restrict__ b1,    // 512 fp32
    ushort*       __restrict__ y2,    // N x 512 bf16
    float*        __restrict__ ssq)   // 512 fp32
{
    __shared__ __align__(16) ushort sB[128 * 128];   // 32 KB
    __shared__ float sred[HID];
    const int tid = threadIdx.x;
    const int lane = tid & 63, wv = tid >> 6;
    const int lr = lane & 15, q = lane >> 4;
    const int m0 = blockIdx.x << 7;
    const int mw = m0 + (wv << 5);

    #pragma unroll
    for (int i = tid; i < HID; i += 256) sred[i] = 0.f;

    // A fragments: lane holds row (mw + rt*16 + lr), k = ks*32 + q*8 .. +8
    bf16x8 af[2][4];
    {
        const ushort* a0 = y1 + (size_t)(mw + lr) * DIM + (q << 3);
        #pragma unroll
        for (int rt = 0; rt < 2; ++rt)
            #pragma unroll
            for (int ks = 0; ks < 4; ++ks)
                af[rt][ks] = *(const bf16x8*)(a0 + rt * 16 * DIM + ks * 32);
    }

    #pragma unroll 1
    for (int nt = 0; nt < 4; ++nt) {
        // stage B n-tile [nt*128 .. +128) x K=128 into LDS, XOR-swizzled
        #pragma unroll
        for (int i0 = 0; i0 < 2048; i0 += 256) {
            int i = i0 + tid;
            int row = i >> 4, c = i & 15;
            *(uint4*)(sB + row * 128 + ((c ^ (row & 15)) << 3)) =
                *(const uint4*)(w1t + (size_t)((nt << 7) + row) * DIM + (c << 3));
        }
        // bias loads in flight during staging/MFMA (8 VGPR, transient)
        float b1v[8];
        #pragma unroll
        for (int ct = 0; ct < 8; ++ct) b1v[ct] = b1[(nt << 7) + (ct << 4) + lr];
        __syncthreads();

        f32x4 acc[2][8];
        #pragma unroll
        for (int ct = 0; ct < 8; ++ct) { f32x4 z = {0.f,0.f,0.f,0.f}; acc[0][ct] = z; acc[1][ct] = z; }

        #pragma unroll
        for (int ct = 0; ct < 8; ++ct)
            #pragma unroll
            for (int ks = 0; ks < 4; ++ks) {
                const int cidx = ((((ks << 2) + q) ^ lr) << 3);
                bf16x8 bfv = *(const bf16x8*)(sB + ((ct << 4) + lr) * 128 + cidx);
                acc[0][ct] = __builtin_amdgcn_mfma_f32_16x16x32_bf16(af[0][ks], bfv, acc[0][ct], 0, 0, 0);
                acc[1][ct] = __builtin_amdgcn_mfma_f32_16x16x32_bf16(af[1][ks], bfv, acc[1][ct], 0, 0, 0);
            }

        // epilogue for this n-tile: bias + fast GELU + store + ssq partials
        #pragma unroll
        for (int ct = 0; ct < 8; ++ct) {
            const int col = (nt << 7) + (ct << 4) + lr;
            float ss = 0.f;
            #pragma unroll
            for (int rt = 0; rt < 2; ++rt) {
                #pragma unroll
                for (int r = 0; r < 4; ++r) {
                    float g = gelu_f(acc[rt][ct][r] + b1v[ct]);
                    y2[(size_t)(mw + rt * 16 + (q << 2) + r) * HID + col] = f2bf(g);
                    ss += g * g;
                }
            }
            ss += __shfl_xor(ss, 16);
            ss += __shfl_xor(ss, 32);
            if (q == 0) atomicAdd(&sred[col], ss);
        }
        __syncthreads();
    }

    #pragma unroll
    for (int i = tid; i < HID; i += 256) atomicAdd(&ssq[i], sred[i]);
}

// ---------------------------------------------------------------------------
// GRN scale: s[c] = grn_g[c] * nx[c] + 1
// ---------------------------------------------------------------------------
__global__ void grn_prep_kernel(const float* __restrict__ ssq,
                                const float* __restrict__ grn_g,
                                float* __restrict__ s)
{
    __shared__ float red[9];
    const int tid = threadIdx.x;
    const float gx = sqrtf(ssq[tid]);
    float v = gx;
    #pragma unroll
    for (int m = 1; m < 64; m <<= 1) v += __shfl_xor(v, m);
    if ((tid & 63) == 0) red[tid >> 6] = v;
    __syncthreads();
    if (tid == 0) {
        float t = 0.f;
        for (int i = 0; i < 8; ++i) t += red[i];
        red[8] = t;
    }
    __syncthreads();
    const float mean = red[8] * (1.f / 512.f);
    s[tid] = grn_g[tid] * (gx / (mean + 1e-6f)) + 1.0f;
}

// ---------------------------------------------------------------------------
// Fold GRN scale into w2 (transposed, n-major, bf16) + constant bias vector
// ---------------------------------------------------------------------------
__global__ __launch_bounds__(256) void prep_w2_kernel(
    const float* __restrict__ s,      // 512
    const float* __restrict__ w2,     // 512 x 128 fp32 (k-major)
    const float* __restrict__ grn_b,  // 512 fp32
    const float* __restrict__ b2,     // 128 fp32
    ushort*      __restrict__ w2st,   // 128 x 512 bf16 (n-major, scaled)
    float*       __restrict__ bvec)   // 128 fp32
{
    __shared__ float r4[4];
    const int j = blockIdx.x;
    const int tid = threadIdx.x;
    float part = 0.f;
    for (int k = tid; k < HID; k += 256) {
        float wv = w2[k * 128 + j];
        w2st[j * HID + k] = f2bf(s[k] * wv);
        part += grn_b[k] * wv;
    }
    #pragma unroll
    for (int m = 1; m < 64; m <<= 1) part += __shfl_xor(part, m);
    if ((tid & 63) == 0) r4[tid >> 6] = part;
    __syncthreads();
    if (tid == 0)
        bvec[j] = r4[0] + r4[1] + r4[2] + r4[3] + b2[j];
}

// ---------------------------------------------------------------------------
// GEMM2 v5 = v3 structure (measured best; round-3 reg-prefetch reverted).
// B-only LDS staging (32KB per K-chunk, XOR-swizzled), A direct global->reg
// issued before the barrier (HBM latency hides under stage+sync).
// out = y2_grn @ w2 + bvec + residual (GRN scale folded into w2st).
// grid = NPTS/128.
// ---------------------------------------------------------------------------
__global__ __launch_bounds__(256) void gemm2_kernel(
    const ushort* __restrict__ y2,      // N x 512 bf16
    const ushort* __restrict__ w2st,    // 128 x 512 bf16 (n-major)
    const float*  __restrict__ bvec,    // 128
    const ushort* __restrict__ resid,   // N x 128 bf16
    float*        __restrict__ outf,    // N x 128 fp32 (or null)
    ushort*       __restrict__ xbfout)  // N x 128 bf16 (or null)
{
    __shared__ __align__(16) ushort sB[128 * 128];   // 32 KB: 128 n x 128 k chunk
    const int tid = threadIdx.x;
    const int lane = tid & 63, wv = tid >> 6;
    const int lr = lane & 15, q = lane >> 4;
    const int m0 = blockIdx.x << 7;
    const int mw = m0 + (wv << 5);

    f32x4 acc[2][8];
    #pragma unroll
    for (int ct = 0; ct < 8; ++ct) { f32x4 z = {0.f,0.f,0.f,0.f}; acc[0][ct] = z; acc[1][ct] = z; }

    const ushort* abase = y2 + (size_t)(mw + lr) * HID + (q << 3);

    #pragma unroll 1
    for (int kk = 0; kk < 4; ++kk) {
        // A frags for this K-chunk: issue first so HBM latency overlaps staging
        bf16x8 af[2][4];
        #pragma unroll
        for (int rt = 0; rt < 2; ++rt)
            #pragma unroll
            for (int ks = 0; ks < 4; ++ks)
                af[rt][ks] = *(const bf16x8*)(abase + rt * 16 * HID + (kk << 7) + ks * 32);

        // stage B chunk: all 128 n-rows, k in [kk*128, kk*128+128)
        #pragma unroll
        for (int i0 = 0; i0 < 2048; i0 += 256) {
            int i = i0 + tid;
            int row = i >> 4, c = i & 15;
            *(uint4*)(sB + row * 128 + ((c ^ (row & 15)) << 3)) =
                *(const uint4*)(w2st + (size_t)row * HID + (kk << 7) + (c << 3));
        }
        __syncthreads();

        #pragma unroll
        for (int ct = 0; ct < 8; ++ct)
            #pragma unroll
            for (int ks = 0; ks < 4; ++ks) {
                const int cidx = ((((ks << 2) + q) ^ lr) << 3);
                bf16x8 bfv = *(const bf16x8*)(sB + ((ct << 4) + lr) * 128 + cidx);
                acc[0][ct] = __builtin_amdgcn_mfma_f32_16x16x32_bf16(af[0][ks], bfv, acc[0][ct], 0, 0, 0);
                acc[1][ct] = __builtin_amdgcn_mfma_f32_16x16x32_bf16(af[1][ks], bfv, acc[1][ct], 0, 0, 0);
            }
        __syncthreads();
    }

    float bv[8];
    #pragma unroll
    for (int ct = 0; ct < 8; ++ct) bv[ct] = bvec[(ct << 4) + lr];

    #pragma unroll
    for (int rt = 0; rt < 2; ++rt)
        #pragma unroll
        for (int r = 0; r < 4; ++r) {
            const int m = mw + (rt << 4) + (q << 2) + r;
            const size_t base = (size_t)m * DIM;
            #pragma unroll
            for (int ct = 0; ct < 8; ++ct) {
                const int j = (ct << 4) + lr;
                float v = acc[rt][ct][r] + bv[ct] + bf2f(resid[base + j]);
                if (outf)   outf[base + j] = v;
                if (xbfout) xbfout[base + j] = f2bf(v);
            }
        }
}

// ---------------------------------------------------------------------------
extern "C" void kernel_launch(void* const* d_in, const int* in_sizes, int n_in,
                              void* d_out, int out_size, void* d_ws, size_t ws_size,
                              hipStream_t stream)
{
    const float* feats = (const float*)d_in[0];
    const float* w_dw  = (const float*)d_in[1];
    const float* b_dw  = (const float*)d_in[2];
    const float* ln_g  = (const float*)d_in[3];
    const float* ln_b  = (const float*)d_in[4];
    const float* w1    = (const float*)d_in[5];
    const float* b1    = (const float*)d_in[6];
    const float* grn_g = (const float*)d_in[7];
    const float* grn_b = (const float*)d_in[8];
    const float* w2    = (const float*)d_in[9];
    const float* b2    = (const float*)d_in[10];
    const int*   nbr   = (const int*)d_in[11];

    char* ws = (char*)d_ws;
    size_t o = 0;
    ushort* y2    = (ushort*)(ws + o); o += (size_t)NPTS * HID * 2;        // 160 MB
    ushort* y1    = (ushort*)(ws + o); o += (size_t)NPTS * DIM * 2;        //  40 MB
    ushort* xbf   = (ushort*)(ws + o); o += (size_t)NPTS * DIM * 2;        //  40 MB
    int*    wl    = (int*)   (ws + o); o += ((size_t)NPTS * 52 + 64) * 4;  //  33 MB
    int*    nrnd  = (int*)   (ws + o); o += (size_t)NPTS * 4;
    ushort* w1t   = (ushort*)(ws + o); o += (size_t)HID * DIM * 2;
    ushort* w2st  = (ushort*)(ws + o); o += (size_t)HID * DIM * 2;
    float*  sbuf  = (float*) (ws + o); o += 2048;
    float*  ssq   = (float*) (ws + o); o += 2048;
    float*  bvec  = (float*) (ws + o); o += 512;

    cast_bf16_kernel<<<NPTS * DIM / 4 / 256, 256, 0, stream>>>(feats, xbf);
    compact2_kernel<<<NPTS / 4, 256, 0, stream>>>(nbr, wl, nrnd);

    for (int l = 0; l < DEPTH; ++l) {
        const float* wdw_l = w_dw  + (size_t)l * KK2 * DIM;
        const float* bdw_l = b_dw  + (size_t)l * DIM;
        const float* lng_l = ln_g  + (size_t)l * DIM;
        const float* lnb_l = ln_b  + (size_t)l * DIM;
        const float* w1_l  = w1    + (size_t)l * DIM * HID;
        const float* b1_l  = b1    + (size_t)l * HID;
        const float* gg_l  = grn_g + (size_t)l * HID;
        const float* gb_l  = grn_b + (size_t)l * HID;
        const float* w2_l  = w2    + (size_t)l * HID * DIM;
        const float* b2_l  = b2    + (size_t)l * DIM;

        w1t_kernel<<<512, 128, 0, stream>>>(w1_l, w1t, ssq);
        dwln3_kernel<<<NPTS / 16, 1024, 0, stream>>>(
            xbf, wl, nrnd, wdw_l, bdw_l, lng_l, lnb_l, y1);
        gemm1_kernel<<<NPTS / 128, 256, 0, stream>>>(y1, w1t, b1_l, y2, ssq);
        grn_prep_kernel<<<1, 512, 0, stream>>>(ssq, gg_l, sbuf);
        prep_w2_kernel<<<128, 256, 0, stream>>>(sbuf, w2_l, gb_l, b2_l, w2st, bvec);
        if (l == 0) {
            gemm2_kernel<<<NPTS / 128, 256, 0, stream>>>(
                y2, w2st, bvec, xbf, nullptr, xbf);
        } else {
            gemm2_kernel<<<NPTS / 128, 256, 0, stream>>>(
                y2, w2st, bvec, xbf, (float*)d_out, nullptr);
        }
    }
}